// Round 1
// 10695.721 us; speedup vs baseline: 1.8326x; 1.8326x over previous
//
#include <hip/hip_runtime.h>

// ---------------------------------------------------------------------------
// SequencePredictorRNN: LSTM(1024 steps, batch 128, d=1024) + 512-class readout
//
// Persistent kernel, 128 blocks x 512 threads. Block b owns hidden units
// [8b,8b+8) -> 32 packed gate columns in LDS; XG input-gate table (512 classes)
// precomputed in LDS.
//
// This revision targets the latency-bound barrier (prev: 19 us/step, MfmaUtil
// 2.5%):
//  * relaxed spin polls (the old ACQUIRE polls emitted buffer_inv sc1 -> whole
//    per-XCD L2 invalidated EVERY poll iteration, thrashing co-resident
//    blocks' h reads). Now: relaxed polls + ONE acquire fence at exit.
//  * one release-RMW at arrival (no __threadfence pairs -> one wbl2/step).
//  * 8 arrival counters on separate 128B lines (16 RMWs each vs 128 on one).
//  * tiled h layout hT[u>>3][row][u&7]: block-private 2KB write region per
//    step (kills cross-XCD false sharing; 790MB->~530MB writes), reads stay
//    16B/lane contiguous and better coalesced than row-major.
//  * logits MFMA moved between arrival and spin-exit (hidden under barrier
//    latency). Requires 3-deep h ring: buf[p%3] is only overwritten at iter
//    p+2, which needs barrier p+1, which needs this block's logits-p done.
//  * nontemporal out stores (don't dirty L2 -> cheaper wbl2 at arrival).
// Workspace: 1KB counters + 3 x 128x1024 fp16 h buffers = 769 KB.
// ---------------------------------------------------------------------------

typedef _Float16 h8v  __attribute__((ext_vector_type(8)));   // 8 x fp16 (4 VGPR)
typedef float    f32x4 __attribute__((ext_vector_type(4)));

#define SEQL  1024
#define BATCH 128
#define DM    1024
#define NC    512
#define PAD   1032
#define HELEMS (BATCH * DM)    // fp16 elems per h buffer (256 KB)

__device__ __forceinline__ float sigm(float x)   { return 1.0f / (1.0f + __expf(-x)); }
__device__ __forceinline__ float tanh_f(float x) { return 1.0f - 2.0f / (__expf(2.0f * x) + 1.0f); }

__device__ __forceinline__ h8v ld8f_cvt(const float* p) {
    const float4 a = ((const float4*)p)[0];
    const float4 b = ((const float4*)p)[1];
    h8v v;
    v[0] = (_Float16)a.x; v[1] = (_Float16)a.y;
    v[2] = (_Float16)a.z; v[3] = (_Float16)a.w;
    v[4] = (_Float16)b.x; v[5] = (_Float16)b.y;
    v[6] = (_Float16)b.z; v[7] = (_Float16)b.w;
    return v;
}

__global__ __launch_bounds__(512) void lstm_all_kernel(
    const int*   __restrict__ x,     const float* __restrict__ emb,
    const float* __restrict__ Wih,   const float* __restrict__ Whh,
    const float* __restrict__ bih,   const float* __restrict__ bhh,
    const float* __restrict__ Wpred, const float* __restrict__ bpred,
    _Float16* __restrict__ hbuf, unsigned* __restrict__ cnt,
    float* __restrict__ out)
{
    __shared__ _Float16 Ws[32 * PAD];      // W_ih slice, then W_hh slice
    __shared__ _Float16 Wp[16 * PAD];      // W_pred slice (16 x 1024)
    __shared__ _Float16 XGs[512 * 32];     // XG table: class x 32 packed cols
    __shared__ float biasS[32];

    const int tid  = threadIdx.x;
    const int b    = blockIdx.x;
    const int u0   = b * 8;                 // first hidden unit owned
    const int C0   = (b & 31) * 16;         // logits column base
    const int wave = tid >> 6, lane = tid & 63;
    const int q = lane >> 4, p15 = lane & 15;

    // ---- Phase A: stage W_ih slice, W_pred slice, biases ----
    for (int idx = tid; idx < 32 * 128; idx += 512) {
        int c = idx >> 7, kc = idx & 127;
        int g = c >> 3, j = c & 7;
        *(h8v*)&Ws[c * PAD + kc * 8] =
            ld8f_cvt(&Wih[(g * 1024 + u0 + j) * DM + kc * 8]);
    }
    for (int idx = tid; idx < 16 * 128; idx += 512) {
        int rr = idx >> 7, kc = idx & 127;
        *(h8v*)&Wp[rr * PAD + kc * 8] =
            ld8f_cvt(&Wpred[(C0 + rr) * DM + kc * 8]);
    }
    if (tid < 32) {
        int g = tid >> 3, j = tid & 7;
        int r = g * 1024 + u0 + j;
        biasS[tid] = bih[r] + bhh[r];
    }
    __syncthreads();

    const _Float16* wsp0 = &Ws[p15 * PAD + q * 8];          // packed cols 0..15
    const _Float16* wsp1 = &Ws[(16 + p15) * PAD + q * 8];   // packed cols 16..31
    const _Float16* wpp  = &Wp[p15 * PAD + q * 8];

    // ---- Phase B: XG table. Each wave: 64 classes (4 m-tiles of 16) ----
#pragma unroll
    for (int mt = 0; mt < 4; ++mt) {
        f32x4 a0 = {0.f,0.f,0.f,0.f}, a1 = {0.f,0.f,0.f,0.f};
        const float* ep = emb + (wave * 64 + mt * 16 + p15) * DM + q * 8;
#pragma unroll 8
        for (int ks = 0; ks < 32; ++ks) {
            h8v av = ld8f_cvt(ep + ks * 32);
            a0 = __builtin_amdgcn_mfma_f32_16x16x32_f16(
                av, *(const h8v*)(wsp0 + ks * 32), a0, 0, 0, 0);
            a1 = __builtin_amdgcn_mfma_f32_16x16x32_f16(
                av, *(const h8v*)(wsp1 + ks * 32), a1, 0, 0, 0);
        }
#pragma unroll
        for (int reg = 0; reg < 4; ++reg) {
            int row = wave * 64 + mt * 16 + q * 4 + reg;    // class index
            XGs[row * 32 + p15]      = (_Float16)(a0[reg] + biasS[p15]);
            XGs[row * 32 + 16 + p15] = (_Float16)(a1[reg] + biasS[16 + p15]);
        }
    }
    __syncthreads();

    // ---- Phase C: restage Ws with W_hh slice ----
    for (int idx = tid; idx < 32 * 128; idx += 512) {
        int c = idx >> 7, kc = idx & 127;
        int g = c >> 3, j = c & 7;
        *(h8v*)&Ws[c * PAD + kc * 8] =
            ld8f_cvt(&Whh[(g * 1024 + u0 + j) * DM + kc * 8]);
    }
    __syncthreads();

    const int wA = (b >> 5) * 2;                       // logits waves
    const bool isLog = (wave == wA) || (wave == wA + 1);
    const float bp_l = isLog ? bpred[C0 + p15] : 0.f;

    float csr[4] = {0.f, 0.f, 0.f, 0.f};               // cell state (fp32)

    // reader base offset into tiled h: element (k>>3)*1024 + row*8 (+k&7)
    const int hlane = q * 1024 + (wave * 16 + p15) * 8;

#pragma unroll 1
    for (int p = 0; p <= SEQL; ++p) {
        const _Float16* hprevT = hbuf + (p % 3) * HELEMS;
        _Float16*       hnewT  = hbuf + ((p + 1) % 3) * HELEMS;
        const bool doGates = (p < SEQL);
        const bool doLogW  = (p >= 1) && isLog;

        if (doGates) {
            f32x4 accA, accB;
#pragma unroll
            for (int reg = 0; reg < 4; ++reg) {
                int row = wave * 16 + q * 4 + reg;     // batch row
                int cls = x[p * BATCH + row];
                accA[reg] = (float)XGs[cls * 32 + p15];
                accB[reg] = (float)XGs[cls * 32 + 16 + p15];
            }
            const _Float16* hb = hprevT + hlane;
#pragma unroll 1
            for (int kc = 0; kc < 4; ++kc) {
                h8v af[8];
#pragma unroll
                for (int jj = 0; jj < 8; ++jj)
                    af[jj] = *(const h8v*)(hb + (kc * 32 + jj * 4) * 1024);
#pragma unroll
                for (int jj = 0; jj < 8; ++jj) {
                    int ks = kc * 8 + jj;
                    accA = __builtin_amdgcn_mfma_f32_16x16x32_f16(
                        af[jj], *(const h8v*)(wsp0 + ks * 32), accA, 0, 0, 0);
                    accB = __builtin_amdgcn_mfma_f32_16x16x32_f16(
                        af[jj], *(const h8v*)(wsp1 + ks * 32), accB, 0, 0, 0);
                }
            }
            // cell update: lane p15<8 owns unit j=p15; lanes p15+8 hold f,o
#pragma unroll
            for (int reg = 0; reg < 4; ++reg) {
                float fv = __shfl_xor(accA[reg], 8, 64);
                float ov = __shfl_xor(accB[reg], 8, 64);
                if (p15 < 8) {
                    float iv = sigm(accA[reg]);
                    float ff = sigm(fv);
                    float gv = tanh_f(accB[reg]);
                    float oo = sigm(ov);
                    float c  = ff * csr[reg] + iv * gv;
                    csr[reg] = c;
                    int row = wave * 16 + q * 4 + reg;
                    // tiled: block-private contiguous 2KB region
                    hnewT[b * 1024 + row * 8 + p15] = (_Float16)(oo * tanh_f(c));
                }
            }
            __syncthreads();               // drains this block's h stores (vmcnt0)
            if (tid == 0)                  // release-RMW: one wbl2, then add @ LLC
                __hip_atomic_fetch_add(&cnt[(b & 7) * 32], 1u,
                                       __ATOMIC_RELEASE, __HIP_MEMORY_SCOPE_AGENT);
        }

        // ---- logits for timestep p-1, hidden under the barrier wait ----
        if (doLogW) {
            f32x4 accL = {0.f,0.f,0.f,0.f};
            const _Float16* hb = hprevT + hlane;
#pragma unroll 1
            for (int kc = 0; kc < 4; ++kc) {
                h8v af[8];
#pragma unroll
                for (int jj = 0; jj < 8; ++jj)
                    af[jj] = *(const h8v*)(hb + (kc * 32 + jj * 4) * 1024);
#pragma unroll
                for (int jj = 0; jj < 8; ++jj)
                    accL = __builtin_amdgcn_mfma_f32_16x16x32_f16(
                        af[jj], *(const h8v*)(wpp + (kc * 8 + jj) * 32), accL, 0, 0, 0);
            }
            const int s = p - 1;
#pragma unroll
            for (int reg = 0; reg < 4; ++reg) {
                int row = wave * 16 + q * 4 + reg;      // batch row
                __builtin_nontemporal_store(accL[reg] + bp_l,
                    &out[row * (SEQL * NC) + s * NC + C0 + p15]);
            }
        }

        if (doGates) {
            // ---- barrier exit: RELAXED polls (no L2 inv per poll!) ----
            if (tid < 8) {
                const unsigned target = (unsigned)(p + 1) * 16u;
                while (__hip_atomic_load(&cnt[tid * 32], __ATOMIC_RELAXED,
                                         __HIP_MEMORY_SCOPE_AGENT) < target)
                    __builtin_amdgcn_s_sleep(1);
                // single acquire: one buffer_inv for the whole step
                __builtin_amdgcn_fence(__ATOMIC_ACQUIRE, "agent");
            }
            __syncthreads();
        }
    }
}

// ---------------------------------------------------------------------------
extern "C" void kernel_launch(void* const* d_in, const int* in_sizes, int n_in,
                              void* d_out, int out_size, void* d_ws, size_t ws_size,
                              hipStream_t stream) {
    (void)in_sizes; (void)n_in; (void)out_size; (void)ws_size;
    const int*   x     = (const int*)  d_in[0];
    const float* emb   = (const float*)d_in[1];
    const float* Wih   = (const float*)d_in[2];
    const float* Whh   = (const float*)d_in[3];
    const float* bih   = (const float*)d_in[4];
    const float* bhh   = (const float*)d_in[5];
    const float* Wpred = (const float*)d_in[6];
    const float* bpred = (const float*)d_in[7];
    float* out = (float*)d_out;

    unsigned*  cnt  = (unsigned*)d_ws;                   // 8 counters, 128B apart
    _Float16*  hbuf = (_Float16*)((char*)d_ws + 1024);   // 3 x 128x1024 fp16 ring

    // zero counters + h ring buffer 0 (buffers 1,2 are fully written before read)
    hipMemsetAsync(d_ws, 0, 1024 + HELEMS * 2, stream);

    hipLaunchKernelGGL(lstm_all_kernel, dim3(128), dim3(512), 0, stream,
                       x, emb, Wih, Whh, bih, bhh, Wpred, bpred,
                       hbuf, cnt, out);
}

// Round 2
// 8447.055 us; speedup vs baseline: 2.3205x; 1.2662x over previous
//
#include <hip/hip_runtime.h>

// ---------------------------------------------------------------------------
// SequencePredictorRNN: LSTM(1024 steps, batch 128, d=1024) + 512-class readout
//
// Persistent kernel, 128 blocks x 512 threads. Block b owns hidden units
// [8b,8b+8) -> 32 packed gate columns in LDS; XG input-gate table (512 classes)
// precomputed in LDS. Logits MFMA hidden under the barrier wait (3-deep h ring).
//
// R2: remove the last L2-writeback from the per-step critical path.
//  * h stores are agent-scope write-through (global_store_short sc1) via
//    __hip_atomic_store relaxed/agent -> compiler-tracked, drained to the LLC
//    by the vmcnt(0) that __syncthreads emits.
//  * arrival RMW downgraded RELEASE -> RELAXED: no buffer_wbl2 (XCD dirty-L2
//    flush, ~64KB/step) on the critical path. Visibility: sc1 stores ack at
//    LLC before the RMW issues; spinners acquire-fence (buffer_inv sc1, drops
//    clean lines only) before reading h, so no stale L2.
//  * next-step XG gate values (x[] lookup + XGs LDS gather -> 8 fp32 regs)
//    prefetched BEFORE the spin: x and XGs are static, so the post-barrier
//    critical path starts directly with h loads.
// Workspace: 1KB counters + 3 x 128x1024 fp16 h buffers = 769 KB.
// ---------------------------------------------------------------------------

typedef _Float16 h8v  __attribute__((ext_vector_type(8)));   // 8 x fp16 (4 VGPR)
typedef float    f32x4 __attribute__((ext_vector_type(4)));

#define SEQL  1024
#define BATCH 128
#define DM    1024
#define NC    512
#define PAD   1032
#define HELEMS (BATCH * DM)    // fp16 elems per h buffer (256 KB)

__device__ __forceinline__ float sigm(float x)   { return 1.0f / (1.0f + __expf(-x)); }
__device__ __forceinline__ float tanh_f(float x) { return 1.0f - 2.0f / (__expf(2.0f * x) + 1.0f); }

__device__ __forceinline__ h8v ld8f_cvt(const float* p) {
    const float4 a = ((const float4*)p)[0];
    const float4 b = ((const float4*)p)[1];
    h8v v;
    v[0] = (_Float16)a.x; v[1] = (_Float16)a.y;
    v[2] = (_Float16)a.z; v[3] = (_Float16)a.w;
    v[4] = (_Float16)b.x; v[5] = (_Float16)b.y;
    v[6] = (_Float16)b.z; v[7] = (_Float16)b.w;
    return v;
}

// agent-scope write-through fp16 store: emits global_store_short ... sc1,
// tracked by the compiler's waitcnt insertion (unlike inline asm).
__device__ __forceinline__ void st_h_agent(_Float16* p, float v) {
    _Float16 hv = (_Float16)v;
    unsigned short u = __builtin_bit_cast(unsigned short, hv);
    __hip_atomic_store((unsigned short*)p, u, __ATOMIC_RELAXED,
                       __HIP_MEMORY_SCOPE_AGENT);
}

__global__ __launch_bounds__(512) void lstm_all_kernel(
    const int*   __restrict__ x,     const float* __restrict__ emb,
    const float* __restrict__ Wih,   const float* __restrict__ Whh,
    const float* __restrict__ bih,   const float* __restrict__ bhh,
    const float* __restrict__ Wpred, const float* __restrict__ bpred,
    _Float16* __restrict__ hbuf, unsigned* __restrict__ cnt,
    float* __restrict__ out)
{
    __shared__ _Float16 Ws[32 * PAD];      // W_ih slice, then W_hh slice
    __shared__ _Float16 Wp[16 * PAD];      // W_pred slice (16 x 1024)
    __shared__ _Float16 XGs[512 * 32];     // XG table: class x 32 packed cols
    __shared__ float biasS[32];

    const int tid  = threadIdx.x;
    const int b    = blockIdx.x;
    const int u0   = b * 8;                 // first hidden unit owned
    const int C0   = (b & 31) * 16;         // logits column base
    const int wave = tid >> 6, lane = tid & 63;
    const int q = lane >> 4, p15 = lane & 15;

    // ---- Phase A: stage W_ih slice, W_pred slice, biases ----
    for (int idx = tid; idx < 32 * 128; idx += 512) {
        int c = idx >> 7, kc = idx & 127;
        int g = c >> 3, j = c & 7;
        *(h8v*)&Ws[c * PAD + kc * 8] =
            ld8f_cvt(&Wih[(g * 1024 + u0 + j) * DM + kc * 8]);
    }
    for (int idx = tid; idx < 16 * 128; idx += 512) {
        int rr = idx >> 7, kc = idx & 127;
        *(h8v*)&Wp[rr * PAD + kc * 8] =
            ld8f_cvt(&Wpred[(C0 + rr) * DM + kc * 8]);
    }
    if (tid < 32) {
        int g = tid >> 3, j = tid & 7;
        int r = g * 1024 + u0 + j;
        biasS[tid] = bih[r] + bhh[r];
    }
    __syncthreads();

    const _Float16* wsp0 = &Ws[p15 * PAD + q * 8];          // packed cols 0..15
    const _Float16* wsp1 = &Ws[(16 + p15) * PAD + q * 8];   // packed cols 16..31
    const _Float16* wpp  = &Wp[p15 * PAD + q * 8];

    // ---- Phase B: XG table. Each wave: 64 classes (4 m-tiles of 16) ----
#pragma unroll
    for (int mt = 0; mt < 4; ++mt) {
        f32x4 a0 = {0.f,0.f,0.f,0.f}, a1 = {0.f,0.f,0.f,0.f};
        const float* ep = emb + (wave * 64 + mt * 16 + p15) * DM + q * 8;
#pragma unroll 8
        for (int ks = 0; ks < 32; ++ks) {
            h8v av = ld8f_cvt(ep + ks * 32);
            a0 = __builtin_amdgcn_mfma_f32_16x16x32_f16(
                av, *(const h8v*)(wsp0 + ks * 32), a0, 0, 0, 0);
            a1 = __builtin_amdgcn_mfma_f32_16x16x32_f16(
                av, *(const h8v*)(wsp1 + ks * 32), a1, 0, 0, 0);
        }
#pragma unroll
        for (int reg = 0; reg < 4; ++reg) {
            int row = wave * 64 + mt * 16 + q * 4 + reg;    // class index
            XGs[row * 32 + p15]      = (_Float16)(a0[reg] + biasS[p15]);
            XGs[row * 32 + 16 + p15] = (_Float16)(a1[reg] + biasS[16 + p15]);
        }
    }
    __syncthreads();

    // ---- Phase C: restage Ws with W_hh slice ----
    for (int idx = tid; idx < 32 * 128; idx += 512) {
        int c = idx >> 7, kc = idx & 127;
        int g = c >> 3, j = c & 7;
        *(h8v*)&Ws[c * PAD + kc * 8] =
            ld8f_cvt(&Whh[(g * 1024 + u0 + j) * DM + kc * 8]);
    }
    __syncthreads();

    const int wA = (b >> 5) * 2;                       // logits waves
    const bool isLog = (wave == wA) || (wave == wA + 1);
    const float bp_l = isLog ? bpred[C0 + p15] : 0.f;

    float csr[4] = {0.f, 0.f, 0.f, 0.f};               // cell state (fp32)

    // reader base offset into tiled h: element (k>>3)*1024 + row*8 (+k&7)
    const int hlane = q * 1024 + (wave * 16 + p15) * 8;

    // prefetched XG gate values for the upcoming step (x, XGs are static)
    f32x4 pA, pB;
#pragma unroll
    for (int reg = 0; reg < 4; ++reg) {
        int row = wave * 16 + q * 4 + reg;
        int cls = x[row];                               // step 0
        pA[reg] = (float)XGs[cls * 32 + p15];
        pB[reg] = (float)XGs[cls * 32 + 16 + p15];
    }

#pragma unroll 1
    for (int p = 0; p <= SEQL; ++p) {
        const _Float16* hprevT = hbuf + (p % 3) * HELEMS;
        _Float16*       hnewT  = hbuf + ((p + 1) % 3) * HELEMS;
        const bool doGates = (p < SEQL);
        const bool doLogW  = (p >= 1) && isLog;

        if (doGates) {
            f32x4 accA = pA, accB = pB;
            const _Float16* hb = hprevT + hlane;
#pragma unroll 1
            for (int kc = 0; kc < 4; ++kc) {
                h8v af[8];
#pragma unroll
                for (int jj = 0; jj < 8; ++jj)
                    af[jj] = *(const h8v*)(hb + (kc * 32 + jj * 4) * 1024);
#pragma unroll
                for (int jj = 0; jj < 8; ++jj) {
                    int ks = kc * 8 + jj;
                    accA = __builtin_amdgcn_mfma_f32_16x16x32_f16(
                        af[jj], *(const h8v*)(wsp0 + ks * 32), accA, 0, 0, 0);
                    accB = __builtin_amdgcn_mfma_f32_16x16x32_f16(
                        af[jj], *(const h8v*)(wsp1 + ks * 32), accB, 0, 0, 0);
                }
            }
            // cell update: lane p15<8 owns unit j=p15; lanes p15+8 hold f,o
#pragma unroll
            for (int reg = 0; reg < 4; ++reg) {
                float fv = __shfl_xor(accA[reg], 8, 64);
                float ov = __shfl_xor(accB[reg], 8, 64);
                if (p15 < 8) {
                    float iv = sigm(accA[reg]);
                    float ff = sigm(fv);
                    float gv = tanh_f(accB[reg]);
                    float oo = sigm(ov);
                    float c  = ff * csr[reg] + iv * gv;
                    csr[reg] = c;
                    int row = wave * 16 + q * 4 + reg;
                    // tiled block-private 2KB region; write-through to LLC
                    st_h_agent(&hnewT[b * 1024 + row * 8 + p15],
                               oo * tanh_f(c));
                }
            }
            __syncthreads();               // per-wave vmcnt(0): sc1 stores at LLC
            if (tid == 0)                  // RELAXED arrival: no buffer_wbl2
                __hip_atomic_fetch_add(&cnt[(b & 7) * 32], 1u,
                                       __ATOMIC_RELAXED, __HIP_MEMORY_SCOPE_AGENT);

            // prefetch next step's XG gate values (static data; hides under spin)
            if (p + 1 < SEQL) {
#pragma unroll
                for (int reg = 0; reg < 4; ++reg) {
                    int row = wave * 16 + q * 4 + reg;
                    int cls = x[(p + 1) * BATCH + row];
                    pA[reg] = (float)XGs[cls * 32 + p15];
                    pB[reg] = (float)XGs[cls * 32 + 16 + p15];
                }
            }
        }

        // ---- logits for timestep p-1, hidden under the barrier wait ----
        if (doLogW) {
            f32x4 accL = {0.f,0.f,0.f,0.f};
            const _Float16* hb = hprevT + hlane;
#pragma unroll 1
            for (int kc = 0; kc < 4; ++kc) {
                h8v af[8];
#pragma unroll
                for (int jj = 0; jj < 8; ++jj)
                    af[jj] = *(const h8v*)(hb + (kc * 32 + jj * 4) * 1024);
#pragma unroll
                for (int jj = 0; jj < 8; ++jj)
                    accL = __builtin_amdgcn_mfma_f32_16x16x32_f16(
                        af[jj], *(const h8v*)(wpp + (kc * 8 + jj) * 32), accL, 0, 0, 0);
            }
            const int s = p - 1;
#pragma unroll
            for (int reg = 0; reg < 4; ++reg) {
                int row = wave * 16 + q * 4 + reg;      // batch row
                __builtin_nontemporal_store(accL[reg] + bp_l,
                    &out[row * (SEQL * NC) + s * NC + C0 + p15]);
            }
        }

        if (doGates) {
            // ---- barrier exit: relaxed polls; ONE acquire inv per step ----
            if (tid < 8) {
                const unsigned target = (unsigned)(p + 1) * 16u;
                while (__hip_atomic_load(&cnt[tid * 32], __ATOMIC_RELAXED,
                                         __HIP_MEMORY_SCOPE_AGENT) < target)
                    __builtin_amdgcn_s_sleep(1);
                // buffer_inv sc1: drops clean lines only (dirty logits survive)
                __builtin_amdgcn_fence(__ATOMIC_ACQUIRE, "agent");
            }
            __syncthreads();
        }
    }
}

// ---------------------------------------------------------------------------
extern "C" void kernel_launch(void* const* d_in, const int* in_sizes, int n_in,
                              void* d_out, int out_size, void* d_ws, size_t ws_size,
                              hipStream_t stream) {
    (void)in_sizes; (void)n_in; (void)out_size; (void)ws_size;
    const int*   x     = (const int*)  d_in[0];
    const float* emb   = (const float*)d_in[1];
    const float* Wih   = (const float*)d_in[2];
    const float* Whh   = (const float*)d_in[3];
    const float* bih   = (const float*)d_in[4];
    const float* bhh   = (const float*)d_in[5];
    const float* Wpred = (const float*)d_in[6];
    const float* bpred = (const float*)d_in[7];
    float* out = (float*)d_out;

    unsigned*  cnt  = (unsigned*)d_ws;                   // 8 counters, 128B apart
    _Float16*  hbuf = (_Float16*)((char*)d_ws + 1024);   // 3 x 128x1024 fp16 ring

    // zero counters + h ring buffer 0 (buffers 1,2 are fully written before read)
    hipMemsetAsync(d_ws, 0, 1024 + HELEMS * 2, stream);

    hipLaunchKernelGGL(lstm_all_kernel, dim3(128), dim3(512), 0, stream,
                       x, emb, Wih, Whh, bih, bhh, Wpred, bpred,
                       hbuf, cnt, out);
}